// Round 12
// baseline (17.192 us; speedup 1.0000x reference)
//
#include <hip/hip_runtime.h>
#include <math.h>

#define NV      6890
#define BLOCK   1024
#define NWAVES  (BLOCK / 64)
#define DENSITY 985.0f

typedef float v2f __attribute__((ext_vector_type(2)));

__device__ __forceinline__ float frcp(float x)  { return __builtin_amdgcn_rcpf(x); }
__device__ __forceinline__ float fsqrt(float x) { return __builtin_amdgcn_sqrtf(x); }

__device__ __forceinline__ unsigned bf16rtn_hi(float f) {   // bf16(f) in high 16 bits
    return (__float_as_uint(f) + 0x8000u) & 0xffff0000u;
}
__device__ __forceinline__ unsigned bf16rtn_lo(float f) {   // bf16(f) in low 16 bits
    return (__float_as_uint(f) + 0x8000u) >> 16;
}

__global__ __launch_bounds__(BLOCK) void measure_kernel(
    const float* __restrict__ v,        // (B, NV, 3)
    const int*   __restrict__ faces,    // (F, 3)
    const int*   __restrict__ circ_idx, // (3,)
    const int*   __restrict__ h_idx,    // (2,)
    float*       __restrict__ out,      // (B, 5)
    int F)
{
    // LDS: vslot[i] = { fp32 y , bf16x2 (x,z) } = 8 B  | red (NWAVES*4 floats)
    extern __shared__ float lds[];
    uint2* vslot = reinterpret_cast<uint2*>(lds);
    float* red   = lds + 2 * NV;

    const int b = blockIdx.x;
    const float* vb = v + (size_t)b * NV * 3;

    // ---- staging: float2 global loads -> packed 8B LDS slots (NV even) ----
    {
        const v2f* vb2 = reinterpret_cast<const v2f*>(vb);   // 8B-aligned for all b
        const int NSLOT = NV / 2;
        for (int j = threadIdx.x; j < NSLOT; j += BLOCK) {
            const v2f a = vb2[3 * j + 0];   // (x0, y0)
            const v2f m = vb2[3 * j + 1];   // (z0, x1)
            const v2f c = vb2[3 * j + 2];   // (y1, z1)
            // round-to-nearest bf16 for x,z; y kept exact fp32
            const unsigned p0 = bf16rtn_hi(a.x) | bf16rtn_lo(m.x);
            const unsigned p1 = bf16rtn_hi(m.y) | bf16rtn_lo(c.y);
            vslot[2 * j + 0] = make_uint2(__float_as_uint(a.y), p0);
            vslot[2 * j + 1] = make_uint2(__float_as_uint(c.x), p1);
        }
    }
    __syncthreads();

    const float py0 = __uint_as_float(vslot[circ_idx[0]].x);
    const float py1 = __uint_as_float(vslot[circ_idx[1]].x);
    const float py2 = __uint_as_float(vslot[circ_idx[2]].x);
    const v2f py01 = { py0, py1 };      // planes 0,1 packed; plane 2 scalar

    float vol = 0.0f;
    float circ[3] = {0.0f, 0.0f, 0.0f};

    // one face's full contribution (volume + 3 plane segments)
    auto face_body = [&](int i0, int i1, int i2) {
        const uint2 s0 = vslot[i0];         // one ds_read_b64 per vertex
        const uint2 s1 = vslot[i1];
        const uint2 s2 = vslot[i2];
        const float y0 = __uint_as_float(s0.x);
        const float y1 = __uint_as_float(s1.x);
        const float y2 = __uint_as_float(s2.x);
        const v2f xz0 = { __uint_as_float(s0.y & 0xffff0000u), __uint_as_float(s0.y << 16) };
        const v2f xz1 = { __uint_as_float(s1.y & 0xffff0000u), __uint_as_float(s1.y << 16) };
        const v2f xz2 = { __uint_as_float(s2.y & 0xffff0000u), __uint_as_float(s2.y << 16) };

        // signed volume term: v0 . (v1 x v2)   (x,z bf16-rounded, y exact)
        {
            const float cx = y1 * xz2.y - xz1.y * y2;
            const float cy = xz1.y * xz2.x - xz1.x * xz2.y;
            const float cz = xz1.x * y2 - y1 * xz2.x;
            vol += xz0.x * cx + y0 * cy + xz0.y * cz;
        }

        // plane-invariant per-edge slopes; L = |d_odd| * |g_a - g_b|.
        // NaN-safety invariant: each h_i is built DIRECTLY from the slopes of
        // its own two crossing edges (crossing => y_a != y_b => slope finite).
        // Degenerate faces (repeated index) put NaN/inf ONLY in h's the
        // selection never picks.  Do NOT derive w1 from w0 - w2.
        const v2f g01 = (xz1 - xz0) * frcp(y0 - y1);
        const v2f g12 = (xz2 - xz1) * frcp(y1 - y2);
        const v2f g20 = (xz0 - xz2) * frcp(y2 - y0);

        const v2f w0 = g01 - g20;           // odd = v0 (edges 01 & 20)
        const v2f w1 = g01 - g12;           // odd = v1 (edges 01 & 12)
        const v2f w2 = g12 - g20;           // odd = v2 (edges 12 & 20)
        const float h0 = fsqrt(fmaf(w0.x, w0.x, w0.y * w0.y));
        const float h1 = fsqrt(fmaf(w1.x, w1.x, w1.y * w1.y));
        const float h2 = fsqrt(fmaf(w2.x, w2.x, w2.y * w2.y));

        // packed d for planes 0,1 (components are separate VGPRs)
        const v2f d0p = (v2f){ y0, y0 } - py01;
        const v2f d1p = (v2f){ y1, y1 } - py01;
        const v2f d2p = (v2f){ y2, y2 } - py01;
        const float d0q = y0 - py2, d1q = y1 - py2, d2q = y2 - py2;

        const float d0s[3] = { d0p.x, d0p.y, d0q };
        const float d1s[3] = { d1p.x, d1p.y, d1q };
        const float d2s[3] = { d2p.x, d2p.y, d2q };

        #pragma unroll
        for (int p = 0; p < 3; ++p) {
            const float d0 = d0s[p];
            const float d1 = d1s[p];
            const float d2 = d2s[p];
            // XOR sign tests on exact y's: ties never count as crossings,
            // so the selected h is always finite.
            const bool b0 = d0 < 0.0f;
            const bool b1 = d1 < 0.0f;
            const bool b2 = d2 < 0.0f;
            const bool c0 = b0 != b1;       // edge v0->v1 crosses
            const bool c1 = b1 != b2;       // edge v1->v2

            // odd vertex: 0 iff c0&!c1, 1 iff c0&c1, 2 iff !c0&c1
            const float dsel = c0 ? (c1 ? d1 : d0) : d2;
            float       hsel = c0 ? (c1 ? h1 : h0) : h2;
            // XOR-consistency: c2 = c0^c1 subset of c0|c1 -> valid = c0|c1
            const bool valid = c0 || c1;
            hsel = valid ? hsel : 0.0f;

            circ[p] = fmaf(fabsf(dsel), hsel, circ[p]);
        }
    };

    // paired contiguous faces: thread q handles faces 2q, 2q+1.
    // 6 indices = 3x int2 loads off one base (offsets 0/8/16).
    const int npairs = F / 2;               // F = 13776 -> 6888
    #pragma unroll 2
    for (int q = threadIdx.x; q < npairs; q += BLOCK) {
        const int2* fp = reinterpret_cast<const int2*>(faces + 6 * q);
        const int2 wA = fp[0];              // i0a, i1a
        const int2 wB = fp[1];              // i2a, i0b
        const int2 wC = fp[2];              // i1b, i2b
        face_body(wA.x, wA.y, wB.x);
        face_body(wB.y, wC.x, wC.y);
    }

    // wave-level reduction (wave = 64)
    #pragma unroll
    for (int off = 32; off > 0; off >>= 1) {
        vol     += __shfl_down(vol,     off);
        circ[0] += __shfl_down(circ[0], off);
        circ[1] += __shfl_down(circ[1], off);
        circ[2] += __shfl_down(circ[2], off);
    }
    const int lane = threadIdx.x & 63;
    const int wid  = threadIdx.x >> 6;
    if (lane == 0) {
        red[wid * 4 + 0] = vol;
        red[wid * 4 + 1] = circ[0];
        red[wid * 4 + 2] = circ[1];
        red[wid * 4 + 3] = circ[2];
    }
    __syncthreads();

    // parallel epilogue: threads 0..3 reduce, thread 4 does height
    const int tid = threadIdx.x;
    if (tid < 4) {
        float s = 0.0f;
        for (int w = 0; w < NWAVES; ++w) s += red[w * 4 + tid];
        if (tid == 0) out[b * 5 + 0] = fabsf(s / 6.0f) * DENSITY;  // mass
        else          out[b * 5 + 1 + tid] = s;                    // circ0..2
    } else if (tid == 4) {
        const float hy0 = __uint_as_float(vslot[h_idx[0]].x);
        const float hy1 = __uint_as_float(vslot[h_idx[1]].x);
        out[b * 5 + 1] = fabsf(hy0 - hy1);
    }
}

extern "C" void kernel_launch(void* const* d_in, const int* in_sizes, int n_in,
                              void* d_out, int out_size, void* d_ws, size_t ws_size,
                              hipStream_t stream) {
    const float* v        = (const float*)d_in[0];
    const int*   faces    = (const int*)d_in[1];
    const int*   circ_idx = (const int*)d_in[2];
    const int*   h_idx    = (const int*)d_in[3];
    float*       out      = (float*)d_out;

    const int B = in_sizes[0] / (NV * 3);   // 256
    const int F = in_sizes[1] / 3;          // 13776

    const size_t lds_bytes = (size_t)(2 * NV + NWAVES * 4) * sizeof(float);
    measure_kernel<<<B, BLOCK, lds_bytes, stream>>>(v, faces, circ_idx, h_idx, out, F);
}

// Round 13
// 16.798 us; speedup vs baseline: 1.0234x; 1.0234x over previous
//
#include <hip/hip_runtime.h>
#include <math.h>

#define NV      6890
#define BLOCK   1024
#define NWAVES  (BLOCK / 64)
#define DENSITY 985.0f

typedef float v2f __attribute__((ext_vector_type(2)));

__device__ __forceinline__ float frcp(float x)  { return __builtin_amdgcn_rcpf(x); }
__device__ __forceinline__ float fsqrt(float x) { return __builtin_amdgcn_sqrtf(x); }

__device__ __forceinline__ unsigned bf16rtn_hi(float f) {   // bf16(f) in high 16 bits
    return (__float_as_uint(f) + 0x8000u) & 0xffff0000u;
}
__device__ __forceinline__ unsigned bf16rtn_lo(float f) {   // bf16(f) in low 16 bits
    return (__float_as_uint(f) + 0x8000u) >> 16;
}

__global__ __launch_bounds__(BLOCK) void measure_kernel(
    const float* __restrict__ v,        // (B, NV, 3)
    const int*   __restrict__ faces,    // (F, 3)
    const int*   __restrict__ circ_idx, // (3,)
    const int*   __restrict__ h_idx,    // (2,)
    float*       __restrict__ out,      // (B, 5)
    int F)
{
    // LDS: vslot[i] = { fp32 y , bf16x2 (x,z) } = 8 B  | red (NWAVES*4 floats)
    extern __shared__ float lds[];
    uint2* vslot = reinterpret_cast<uint2*>(lds);
    float* red   = lds + 2 * NV;

    const int b = blockIdx.x;
    const float* vb = v + (size_t)b * NV * 3;

    // ---- staging: float2 global loads -> one uint4 LDS write per 2 verts ----
    {
        const v2f*  vb2 = reinterpret_cast<const v2f*>(vb);  // 8B-aligned for all b
        uint4* vslot4   = reinterpret_cast<uint4*>(vslot);   // 16B per slot-pair
        const int NSLOT = NV / 2;
        for (int j = threadIdx.x; j < NSLOT; j += BLOCK) {
            const v2f a = vb2[3 * j + 0];   // (x0, y0)
            const v2f m = vb2[3 * j + 1];   // (z0, x1)
            const v2f c = vb2[3 * j + 2];   // (y1, z1)
            // round-to-nearest bf16 for x,z; y kept exact fp32
            const unsigned p0 = bf16rtn_hi(a.x) | bf16rtn_lo(m.x);
            const unsigned p1 = bf16rtn_hi(m.y) | bf16rtn_lo(c.y);
            vslot4[j] = make_uint4(__float_as_uint(a.y), p0,
                                   __float_as_uint(c.x), p1);
        }
    }
    __syncthreads();

    const float pys[3] = { __uint_as_float(vslot[circ_idx[0]].x),
                           __uint_as_float(vslot[circ_idx[1]].x),
                           __uint_as_float(vslot[circ_idx[2]].x) };

    float vol = 0.0f;
    float circ[3] = {0.0f, 0.0f, 0.0f};

    #pragma unroll 2
    for (int f = threadIdx.x; f < F; f += BLOCK) {
        const int i0 = faces[3 * f + 0];
        const int i1 = faces[3 * f + 1];
        const int i2 = faces[3 * f + 2];

        const uint2 s0 = vslot[i0];         // one ds_read_b64 per vertex
        const uint2 s1 = vslot[i1];
        const uint2 s2 = vslot[i2];
        const float y0 = __uint_as_float(s0.x);
        const float y1 = __uint_as_float(s1.x);
        const float y2 = __uint_as_float(s2.x);
        const v2f xz0 = { __uint_as_float(s0.y & 0xffff0000u), __uint_as_float(s0.y << 16) };
        const v2f xz1 = { __uint_as_float(s1.y & 0xffff0000u), __uint_as_float(s1.y << 16) };
        const v2f xz2 = { __uint_as_float(s2.y & 0xffff0000u), __uint_as_float(s2.y << 16) };

        // signed volume term: v0 . (v1 x v2)   (x,z bf16-rounded, y exact)
        {
            const float cx = y1 * xz2.y - xz1.y * y2;
            const float cy = xz1.y * xz2.x - xz1.x * xz2.y;
            const float cz = xz1.x * y2 - y1 * xz2.x;
            vol += xz0.x * cx + y0 * cy + xz0.y * cz;
        }

        // plane-invariant per-edge slopes; L = |d_odd| * |g_a - g_b|.
        // NaN-safety invariant: each h_i is built DIRECTLY from the slopes of
        // its own two crossing edges (crossing => y_a != y_b => slope finite).
        // Degenerate faces (repeated index) put NaN/inf ONLY in h's the
        // selection never picks (e.g. i0==i1 => y0==y1 => c0 false => h0,h1
        // unreachable).  Do NOT derive w1 from w0 - w2.
        const v2f g01 = (xz1 - xz0) * frcp(y0 - y1);
        const v2f g12 = (xz2 - xz1) * frcp(y1 - y2);
        const v2f g20 = (xz0 - xz2) * frcp(y2 - y0);

        const v2f w0 = g01 - g20;           // odd = v0 (edges 01 & 20)
        const v2f w1 = g01 - g12;           // odd = v1 (edges 01 & 12)
        const v2f w2 = g12 - g20;           // odd = v2 (edges 12 & 20)
        const float h0 = fsqrt(fmaf(w0.x, w0.x, w0.y * w0.y));
        const float h1 = fsqrt(fmaf(w1.x, w1.x, w1.y * w1.y));
        const float h2 = fsqrt(fmaf(w2.x, w2.x, w2.y * w2.y));

        #pragma unroll
        for (int p = 0; p < 3; ++p) {
            const float py = pys[p];
            const float d0 = y0 - py;
            const float d1 = y1 - py;
            const float d2 = y2 - py;
            // XOR sign tests on exact y's: ties never count as crossings,
            // so the selected h is always finite.
            const bool b0 = d0 < 0.0f;
            const bool b1 = d1 < 0.0f;
            const bool b2 = d2 < 0.0f;
            const bool c0 = b0 != b1;       // edge v0->v1 crosses
            const bool c1 = b1 != b2;       // edge v1->v2
            // c2 = c0 ^ c1 (XOR-consistency) — never computed explicitly.

            // odd vertex: 0 iff c0&!c1, 1 iff c0&c1, 2 iff !c0&c1
            const float dsel = c0 ? (c1 ? d1 : d0) : d2;
            float       hsel = c0 ? (c1 ? h1 : h0) : h2;
            const bool valid = c0 || c1;
            hsel = valid ? hsel : 0.0f;     // guards the no-crossing h2 path

            circ[p] = fmaf(fabsf(dsel), hsel, circ[p]);
        }
    }

    // wave-level reduction (wave = 64)
    #pragma unroll
    for (int off = 32; off > 0; off >>= 1) {
        vol     += __shfl_down(vol,     off);
        circ[0] += __shfl_down(circ[0], off);
        circ[1] += __shfl_down(circ[1], off);
        circ[2] += __shfl_down(circ[2], off);
    }
    const int lane = threadIdx.x & 63;
    const int wid  = threadIdx.x >> 6;
    if (lane == 0) {
        red[wid * 4 + 0] = vol;
        red[wid * 4 + 1] = circ[0];
        red[wid * 4 + 2] = circ[1];
        red[wid * 4 + 3] = circ[2];
    }
    __syncthreads();

    // parallel epilogue: threads 0..3 reduce, thread 4 does height
    const int tid = threadIdx.x;
    if (tid < 4) {
        float s = 0.0f;
        for (int w = 0; w < NWAVES; ++w) s += red[w * 4 + tid];
        if (tid == 0) out[b * 5 + 0] = fabsf(s / 6.0f) * DENSITY;  // mass
        else          out[b * 5 + 1 + tid] = s;                    // circ0..2
    } else if (tid == 4) {
        const float hy0 = __uint_as_float(vslot[h_idx[0]].x);
        const float hy1 = __uint_as_float(vslot[h_idx[1]].x);
        out[b * 5 + 1] = fabsf(hy0 - hy1);
    }
}

extern "C" void kernel_launch(void* const* d_in, const int* in_sizes, int n_in,
                              void* d_out, int out_size, void* d_ws, size_t ws_size,
                              hipStream_t stream) {
    const float* v        = (const float*)d_in[0];
    const int*   faces    = (const int*)d_in[1];
    const int*   circ_idx = (const int*)d_in[2];
    const int*   h_idx    = (const int*)d_in[3];
    float*       out      = (float*)d_out;

    const int B = in_sizes[0] / (NV * 3);   // 256
    const int F = in_sizes[1] / 3;          // 13776

    const size_t lds_bytes = (size_t)(2 * NV + NWAVES * 4) * sizeof(float);
    measure_kernel<<<B, BLOCK, lds_bytes, stream>>>(v, faces, circ_idx, h_idx, out, F);
}